// Round 1
// baseline (397.621 us; speedup 1.0000x reference)
//
#include <hip/hip_runtime.h>

constexpr int kB = 32;
constexpr int kC = 512;
constexpr int kS = 56 * 56;   // 3136
constexpr int kP = 64;
constexpr float kEps = 1e-3f;

constexpr int kST = 64;          // spatial tile per block (16 float4 per thread-slice)
constexpr int kNB = kS / kST;    // 49 tiles per batch
static_assert(kS % kST == 0, "tile must divide S");

typedef float f4v __attribute__((ext_vector_type(4)));

// ---------------------------------------------------------------------------
// Pass A: register-resident x-tile. Block = 512 threads = (c0 = t>>4 in 0..31,
// si = t&15 covering 64 spatial as float4). Each thread holds its 16-float4
// slice of the 64s x 512c tile in VGPRs (64 regs) -- x is read from HBM exactly
// once, no LDS transpose, no per-element DS traffic.
//   phase 1: mask[s] = sum_c x[c,s]*wm[c]   (shfl_xor over c0, LDS combine)
//   wave 0 : local softmax stats (M_loc, Z_loc) + es[s] = exp(mask-M_loc)
//   phase 2: pc[c] = sum_s x[c,s]*es[s]     (register reuse, shfl_xor over si)
// ---------------------------------------------------------------------------
__global__ __launch_bounds__(512, 4)
void k_fused_pass(const float* __restrict__ x, const float* __restrict__ wm,
                  float* __restrict__ pc, float* __restrict__ pmz) {
    __shared__ float swm[kC];
    __shared__ f4v   pmw4[8][16];          // per-wave mask partials (8 waves x 64 s)
    __shared__ f4v   es4[kST / 4];         // exp(mask - M_loc), 16B-aligned

    const int b    = blockIdx.y;
    const int tile = blockIdx.x;
    const int s0   = tile * kST;
    const int t    = threadIdx.x;
    const int si   = t & 15;               // which float4 of the 64-s tile
    const int c0   = t >> 4;               // 0..31
    const int w    = t >> 6;               // wave id 0..7
    const int l    = t & 63;               // lane id

    swm[t & (kC - 1)] = wm[t & (kC - 1)];  // kC == 512 == blockDim
    __syncthreads();

    const float* xb = x + (size_t)b * kC * kS + s0 + si * 4;

    // ---- load register tile (coalesced: 16 lanes x 16B = 256B per c-row) ----
    f4v xt[16];
#pragma unroll
    for (int j = 0; j < 16; ++j)
        xt[j] = *(const f4v*)(xb + (size_t)(c0 + 32 * j) * kS);

    // ---- phase 1: mask partials over this thread's 16 c's ----
    float m0 = 0.f, m1 = 0.f, m2 = 0.f, m3 = 0.f;
#pragma unroll
    for (int j = 0; j < 16; ++j) {
        const float wv = swm[c0 + 32 * j];
        m0 += xt[j].x * wv; m1 += xt[j].y * wv;
        m2 += xt[j].z * wv; m3 += xt[j].w * wv;
    }
    // reduce over the 4 c0-groups within each wave (lanes ^16, ^32)
#pragma unroll
    for (int off = 16; off <= 32; off <<= 1) {
        m0 += __shfl_xor(m0, off); m1 += __shfl_xor(m1, off);
        m2 += __shfl_xor(m2, off); m3 += __shfl_xor(m3, off);
    }
    if (l < 16) pmw4[w][si] = (f4v){m0, m1, m2, m3};
    __syncthreads();

    // ---- wave 0: combine 8 wave-partials, local softmax over 64 s ----
    if (t < kST) {
        const float* pmf = (const float*)pmw4;
        float v = 0.f;
#pragma unroll
        for (int ww = 0; ww < 8; ++ww) v += pmf[ww * kST + t];
        float mx = v;
#pragma unroll
        for (int off = 1; off < 64; off <<= 1) mx = fmaxf(mx, __shfl_xor(mx, off));
        const float e = expf(v - mx);
        float z = e;
#pragma unroll
        for (int off = 1; off < 64; off <<= 1) z += __shfl_xor(z, off);
        ((float*)es4)[t] = e;
        if (t == 0) {
            pmz[(b * kNB + tile) * 2 + 0] = mx;
            pmz[(b * kNB + tile) * 2 + 1] = z;
        }
    }
    __syncthreads();

    // ---- phase 2: context from the SAME registers ----
    const f4v e4 = es4[si];
    float* pco = pc + ((size_t)b * kNB + tile) * kC;
#pragma unroll
    for (int j = 0; j < 16; ++j) {
        float a = xt[j].x * e4.x + xt[j].y * e4.y + xt[j].z * e4.z + xt[j].w * e4.w;
        a += __shfl_xor(a, 1); a += __shfl_xor(a, 2);
        a += __shfl_xor(a, 4); a += __shfl_xor(a, 8);
        if (si == 0) pco[c0 + 32 * j] = a;   // 4 consecutive floats per wave
    }
}

// ---------------------------------------------------------------------------
// Pass B: per batch — combine 49 tile-partials with global softmax rescale,
// then the tiny MLP (w1 -> LN -> ReLU -> w2). One block per b, 512 threads.
// ---------------------------------------------------------------------------
__global__ __launch_bounds__(512)
void k_combine_mlp(const float* __restrict__ pc, const float* __restrict__ pmz,
                   const float* __restrict__ w1, const float* __restrict__ b1,
                   const float* __restrict__ ln_g, const float* __restrict__ ln_b,
                   const float* __restrict__ w2, const float* __restrict__ b2,
                   float* __restrict__ add) {
    const int b = blockIdx.x;
    const int t = threadIdx.x;
    __shared__ float scale[kNB];     // exp(M_i - M)/Z
    __shared__ float ctx[kC];
    __shared__ float hp[kP][9];      // hid partials (pad 9: bank-spread)
    __shared__ float hid[kP];

    // wave 0: global max + Z over 49 tiles
    if (t < 64) {
        const float m1 = (t < kNB) ? pmz[(b * kNB + t) * 2] : -INFINITY;
        float m = m1;
        for (int off = 32; off; off >>= 1) m = fmaxf(m, __shfl_xor(m, off));
        const float e1 = (t < kNB) ? expf(m1 - m) : 0.f;
        float z = 0.f;
        if (t < kNB) z = pmz[(b * kNB + t) * 2 + 1] * e1;
        for (int off = 32; off; off >>= 1) z += __shfl_xor(z, off);
        const float inv = 1.f / z;
        if (t < kNB) scale[t] = e1 * inv;
    }
    __syncthreads();

    // ctx[c] = sum_i pc[i][c] * scale[i]   (coalesced over c)
    {
        float acc = 0.f;
        for (int i = 0; i < kNB; ++i)
            acc += pc[((size_t)b * kNB + i) * kC + t] * scale[i];
        ctx[t] = acc;
    }
    __syncthreads();

    // hid partials: p = t&63, chunk k = t>>6 sums 64 c's (ctx read = broadcast)
    {
        const int p = t & 63, k = t >> 6;
        const float* w1p = w1 + p * kC + k * 64;
        const float* cxp = ctx + k * 64;
        float acc = 0.f;
#pragma unroll 8
        for (int i = 0; i < 64; ++i) acc += w1p[i] * cxp[i];
        hp[p][k] = acc;
    }
    __syncthreads();

    if (t < 64) {
        float h = b1[t];
#pragma unroll
        for (int k = 0; k < 8; ++k) h += hp[t][k];
        // LayerNorm over P=64 (one wave)
        float mu = h;
        for (int off = 32; off; off >>= 1) mu += __shfl_xor(mu, off);
        mu *= (1.f / kP);
        const float d = h - mu;
        float var = d * d;
        for (int off = 32; off; off >>= 1) var += __shfl_xor(var, off);
        var *= (1.f / kP);
        const float hv = d * rsqrtf(var + kEps) * ln_g[t] + ln_b[t];
        hid[t] = fmaxf(hv, 0.f);
    }
    __syncthreads();

    // add[c] = b2[c] + w2[c,:]·hid
    {
        float a = b2[t];
        const float* w2c = w2 + t * kP;
#pragma unroll
        for (int p = 0; p < kP; ++p) a += w2c[p] * hid[p];
        add[b * kC + t] = a;
    }
}

// ---------------------------------------------------------------------------
// Pass C: out = x + gamma*add, float4, nontemporal stores (keep x in L3).
// ---------------------------------------------------------------------------
__global__ __launch_bounds__(256)
void k_out(const float* __restrict__ x, const float* __restrict__ add,
           const float* __restrict__ gamma, float* __restrict__ out) {
    const size_t i4 = (size_t)blockIdx.x * blockDim.x + threadIdx.x;
    const size_t n4 = (size_t)kB * kC * kS / 4;
    if (i4 >= n4) return;
    const int bc = (int)(i4 / (kS / 4));
    const float a = gamma[0] * add[bc];
    f4v xv = ((const f4v*)x)[i4];
    f4v o = {xv.x + a, xv.y + a, xv.z + a, xv.w + a};
    __builtin_nontemporal_store(o, (f4v*)out + i4);
}

extern "C" void kernel_launch(void* const* d_in, const int* in_sizes, int n_in,
                              void* d_out, int out_size, void* d_ws, size_t ws_size,
                              hipStream_t stream) {
    const float* x     = (const float*)d_in[0];
    const float* wm    = (const float*)d_in[1];
    // d_in[2] = bm: uniform pre-softmax shift -> no-op, skipped
    const float* w1    = (const float*)d_in[3];
    const float* b1    = (const float*)d_in[4];
    const float* ln_g  = (const float*)d_in[5];
    const float* ln_b  = (const float*)d_in[6];
    const float* w2    = (const float*)d_in[7];
    const float* b2    = (const float*)d_in[8];
    const float* gamma = (const float*)d_in[9];
    float* out = (float*)d_out;

    float* ws  = (float*)d_ws;
    float* pc  = ws;                               // kB*kNB*kC floats (3.2 MB)
    float* pmz = pc + (size_t)kB * kNB * kC;       // kB*kNB*2 floats
    float* add = pmz + (size_t)kB * kNB * 2;       // kB*kC floats

    k_fused_pass<<<dim3(kNB, kB), 512, 0, stream>>>(x, wm, pc, pmz);
    k_combine_mlp<<<kB, 512, 0, stream>>>(pc, pmz, w1, b1, ln_g, ln_b, w2, b2, add);

    const size_t n4 = (size_t)kB * kC * kS / 4;
    k_out<<<(unsigned)((n4 + 255) / 256), 256, 0, stream>>>(x, add, gamma, out);
}